// Round 3
// baseline (423.259 us; speedup 1.0000x reference)
//
#include <hip/hip_runtime.h>
#include <stdint.h>

typedef _Float16 f16x8 __attribute__((ext_vector_type(8)));
typedef float    f32x4 __attribute__((ext_vector_type(4)));

#define DEVFN static __device__ __forceinline__

DEVFN unsigned short f2hu(float f) {
  _Float16 h = (_Float16)f;
  return __builtin_bit_cast(unsigned short, h);
}
DEVFN float h2f(unsigned short u) {
  return (float)__builtin_bit_cast(_Float16, u);
}
DEVFN float lrelu(float v) { return v >= 0.f ? v : 0.1f * v; }

DEVFN void gload16(const void* g, const void* l) {
  __builtin_amdgcn_global_load_lds(
      (const __attribute__((address_space(1))) void*)(uintptr_t)g,
      (__attribute__((address_space(3))) void*)(uint32_t)(uintptr_t)l,
      16, 0, 0);
}

static constexpr float SCALE_C = 0.029462782549439476f;  // 1/sqrt(128*9)

// ---------------- workspace layout (bytes) ----------------
static constexpr size_t OFF_SIN  = 0;        // 1024 f32: s_in[b,ci] (style per input channel)
static constexpr size_t OFF_DS   = 4096;     // 1024 f32: dscale[b,co] (SCALE*demod)
static constexpr size_t OFF_ZERO = 8192;     // 256B zeros
static constexpr size_t OFF_W2   = 12288;    // 16384 f32: W2[co,ci] = sum_tap w_style^2
static constexpr size_t OFF_WPK  = 77824;    // 4 x 147456 fp16 (dc1,dc2,style,last) packed [co][tap][ci]
static constexpr size_t OFF_WB   = OFF_WPK + 4ull * 147456ull * 2ull;          // w_bottle fp16 [co][256]
static constexpr size_t OFF_XCAT = OFF_WB + 65536;                             // NHWC fp16 [8][128][128][256]
static constexpr size_t OFF_XB   = OFF_XCAT + 8ull * 16384ull * 256ull * 2ull; // [8][128][128][128]
static constexpr size_t OFF_Y1   = OFF_XB + 8ull * 16384ull * 128ull * 2ull;
// total ~135.5 MB; xr reuses XCAT, xglob reuses XB.

// ---------------- prep1: weight packs + s_in + W2 + zeros ----------------
__global__ __launch_bounds__(256) void prep1_kernel(
    const float* __restrict__ xg, const float* __restrict__ w_mod,
    const float* __restrict__ b_mod, const float* __restrict__ w_style,
    const float* __restrict__ w_dc1, const float* __restrict__ w_dc2,
    const float* __restrict__ w_last, const float* __restrict__ w_bottle,
    unsigned short* __restrict__ wpk, unsigned short* __restrict__ wb,
    float* __restrict__ s_in, float* __restrict__ w2buf,
    float* __restrict__ zerob) {
  const int idx = (int)blockIdx.x * 256 + (int)threadIdx.x;
  if (idx < 589824) {  // pack 4 3x3 weights [co][ci][3][3] -> [co][tap][ci] fp16
    const int t  = idx / 147456;
    const int e  = idx - t * 147456;
    const int co = e / 1152;
    const int r  = e - co * 1152;
    const int tap = r >> 7;
    const int ci  = r & 127;
    const float* src = (t == 0) ? w_dc1 : (t == 1) ? w_dc2 : (t == 2) ? w_style : w_last;
    wpk[idx] = f2hu(src[(size_t)(co * 128 + ci) * 9 + tap]);
    return;
  }
  int j = idx - 589824;
  if (j < 32768) { wb[j] = f2hu(w_bottle[j]); return; }  // [co][256] already K-contiguous
  j -= 32768;
  if (j < 65536) {  // one wave per (b,ci): s_in[b,ci] = b_mod[ci] + xg[b,:]·w_mod[ci,:]
    const int pair = j >> 6, ln = j & 63;
    const int b = pair >> 7, ci = pair & 127;
    float st = 0.f;
    for (int m = ln; m < 512; m += 64) st += xg[b * 512 + m] * w_mod[ci * 512 + m];
    for (int off = 32; off > 0; off >>= 1) st += __shfl_down(st, off);
    if (ln == 0) s_in[pair] = st + b_mod[ci];
    return;
  }
  j -= 65536;
  if (j < 16384) {  // W2[co,ci] = sum_tap w_style[co,ci,tap]^2
    float acc = 0.f;
#pragma unroll
    for (int t = 0; t < 9; ++t) { float w = w_style[(size_t)j * 9 + t]; acc += w * w; }
    w2buf[j] = acc;
    return;
  }
  j -= 16384;
  if (j < 64) zerob[j] = 0.f;
}

// ---------------- prep2: dscale[b,co] = SCALE*rsqrt(SCALE^2 * sum_ci s_in^2*W2 + 1e-8) ----------------
__global__ __launch_bounds__(256) void prep2_kernel(
    const float* __restrict__ s_in, const float* __restrict__ w2buf,
    float* __restrict__ dscale) {
  const int j = (int)blockIdx.x * 256 + (int)threadIdx.x;
  const int pair = j >> 6, ln = j & 63;
  const int b = pair >> 7, co = pair & 127;
  const float s0 = s_in[b * 128 + ln];
  const float s1 = s_in[b * 128 + 64 + ln];
  float acc = s0 * s0 * w2buf[co * 128 + ln] + s1 * s1 * w2buf[co * 128 + 64 + ln];
  for (int off = 32; off > 0; off >>= 1) acc += __shfl_down(acc, off);
  if (ln == 0)
    dscale[pair] = SCALE_C * rsqrtf(SCALE_C * SCALE_C * acc + 1e-8f);
}

// ---------------- upsample(bilinear 2x, half-pixel) + concat + NCHW->NHWC fp16 ----------------
__global__ __launch_bounds__(256) void upcat_kernel(
    const float* __restrict__ x2, const float* __restrict__ x1,
    unsigned short* __restrict__ xcat) {
  __shared__ unsigned short lds[256 * 128];  // [c][w]
  const int bid = (int)blockIdx.x;
  const int b = bid >> 7, h = bid & 127;
  const int tid = (int)threadIdx.x;
  const int crow = tid >> 5, wq = tid & 31;

  // x2 channels 0..127
  for (int it = 0; it < 16; ++it) {
    const int c = it * 8 + crow;
    const float4 v = *(const float4*)(x2 + ((size_t)(b * 128 + c) * 16384 + h * 128 + wq * 4));
    ushort4 u;
    u.x = f2hu(v.x); u.y = f2hu(v.y); u.z = f2hu(v.z); u.w = f2hu(v.w);
    *(ushort4*)(&lds[c * 128 + wq * 4]) = u;
  }
  // x1 upsampled -> channels 128..255
  const int m = h >> 1;
  const bool oddh = (h & 1);
  const int ly = oddh ? m : m - 1;
  const float fy = oddh ? 0.25f : 0.75f;
  const int y0 = ly < 0 ? 0 : ly;
  const int y1 = (ly + 1) > 63 ? 63 : (ly + 1);
  for (int it = 0; it < 16; ++it) {
    const int c = it * 8 + crow;
    const float* r0 = x1 + ((size_t)(b * 128 + c) * 4096 + y0 * 64);
    const float* r1 = x1 + ((size_t)(b * 128 + c) * 4096 + y1 * 64);
    ushort4 u;
    unsigned short* up = (unsigned short*)&u;
#pragma unroll
    for (int k = 0; k < 4; ++k) {
      const int w = wq * 4 + k;
      const int n = w >> 1;
      const bool oddw = (w & 1);
      const int lx = oddw ? n : n - 1;
      const float fx = oddw ? 0.25f : 0.75f;
      const int x0i = lx < 0 ? 0 : lx;
      const int x1i = (lx + 1) > 63 ? 63 : (lx + 1);
      const float vy0 = (1.f - fx) * r0[x0i] + fx * r0[x1i];
      const float vy1 = (1.f - fx) * r1[x0i] + fx * r1[x1i];
      up[k] = f2hu((1.f - fy) * vy0 + fy * vy1);
    }
    *(ushort4*)(&lds[(128 + c) * 128 + wq * 4]) = u;
  }
  __syncthreads();
  // write NHWC: [b][h][w][256]
  const int w = tid >> 1;
  const int c0 = (tid & 1) << 7;
  unsigned short* dst = xcat + ((size_t)((b * 128 + h) * 128 + w)) * 256 + c0;
  for (int i0 = 0; i0 < 128; i0 += 8) {
    unsigned int a0 = lds[(c0 + i0 + 0) * 128 + w];
    unsigned int a1 = lds[(c0 + i0 + 1) * 128 + w];
    unsigned int a2 = lds[(c0 + i0 + 2) * 128 + w];
    unsigned int a3 = lds[(c0 + i0 + 3) * 128 + w];
    unsigned int a4 = lds[(c0 + i0 + 4) * 128 + w];
    unsigned int a5 = lds[(c0 + i0 + 5) * 128 + w];
    unsigned int a6 = lds[(c0 + i0 + 6) * 128 + w];
    unsigned int a7 = lds[(c0 + i0 + 7) * 128 + w];
    uint4 q;
    q.x = a0 | (a1 << 16); q.y = a2 | (a3 << 16);
    q.z = a4 | (a5 << 16); q.w = a6 | (a7 << 16);
    *(uint4*)(dst + i0) = q;
  }
}

// ---------------- implicit-GEMM conv, NHWC fp16, MFMA 16x16x32 ----------------
// Tile: BM=256 pixels (2 rows) x BN=128 co, 8 waves (4m x 2n), per-wave 64x64.
// EPI: 0=+bias (bottleneck), 1=+bias,leaky (dc1),
//      2=((y+bias+resid)/sqrt2)*s_in[b,co]  (dc2, fused style input-modulation),
//      3=*dscale[b,co] (modulated conv demod), 4=+bias,leaky, fp32 NCHW out (last)
template <int TAPS, int CTOT, int EPI>
__global__ __launch_bounds__(512, 1) void conv_mfma(
    const unsigned short* __restrict__ Xin, const unsigned short* __restrict__ Wpk,
    const float* __restrict__ bias, const float* __restrict__ sstyle,
    const unsigned short* __restrict__ resid, unsigned short* __restrict__ outb,
    float* __restrict__ outf, const float* __restrict__ zerob) {
  constexpr int ROWS = (TAPS > 1) ? 4 : 2;
  constexpr int WSL  = (TAPS > 1) ? 130 : 128;
  constexpr int XSLOTS = ROWS * WSL * 4;   // 16B slots
  constexpr int WSLOTS = 128 * TAPS * 4;
  constexpr int XBYTES = XSLOTS * 16;
  constexpr int NCB = CTOT / 32;

  __shared__ char smem[XBYTES + WSLOTS * 16];

  const int bid0 = (int)blockIdx.x;
  const int bid  = (bid0 & 7) * 64 + (bid0 >> 3);  // bijective XCD swizzle (512%8==0)
  const int b  = bid >> 6;
  const int h0 = (bid & 63) << 1;

  const int tid = (int)threadIdx.x;
  const int wid = tid >> 6, lane = tid & 63;
  const int wm = wid >> 1, wn = wid & 1;
  const int g = lane >> 4, l15 = lane & 15;

  f32x4 acc[4][4] = {};

  const size_t imgbase = (size_t)b * 16384 * CTOT;

  for (int cb = 0; cb < NCB; ++cb) {
    const int ci0 = cb * 32;
    __syncthreads();
    // ---- stage X tile: [ROWS][WSL][4 chunks of 8 ci], chunk slot c' = c ^ (ws&3)
    for (int sb = wid * 64; sb < XSLOTS; sb += 512) {
      const int s = sb + lane;
      const int rws = s >> 2, cpr = s & 3;
      const int row = rws / WSL;
      const int ws  = rws - row * WSL;
      const int c   = cpr ^ (ws & 3);
      const void* src;
      if (TAPS > 1) {
        const int hrow = h0 + row - 1;
        const int w = ws - 1;
        src = (hrow >= 0 && hrow < 128 && w >= 0 && w < 128)
                  ? (const void*)(Xin + imgbase + (size_t)(hrow * 128 + w) * CTOT + ci0 + c * 8)
                  : (const void*)zerob;
      } else {
        src = Xin + imgbase + (size_t)((h0 + row) * 128 + ws) * CTOT + ci0 + c * 8;
      }
      if ((XSLOTS & 511) == 0 || s < XSLOTS) gload16(src, smem + sb * 16);
    }
    // ---- stage W tile: [128 co][TAPS][4 chunks], chunk slot c' = c ^ (co&3)
    for (int sb = wid * 64; sb < WSLOTS; sb += 512) {
      const int s = sb + lane;
      const int co  = s / (TAPS * 4);
      const int rem = s - co * (TAPS * 4);
      const int tap = rem >> 2, cpr = rem & 3;
      const int c = cpr ^ (co & 3);
      gload16(Wpk + (size_t)(co * TAPS + tap) * CTOT + ci0 + c * 8,
              smem + XBYTES + sb * 16);
    }
    __syncthreads();
    // ---- compute
#pragma unroll
    for (int tap = 0; tap < TAPS; ++tap) {
      f16x8 af[4], bf[4];
#pragma unroll
      for (int mf = 0; mf < 4; ++mf) {
        const int mm = wm * 64 + mf * 16 + l15;
        const int r_out = mm >> 7, w = mm & 127;
        const int rrow = (TAPS > 1) ? (r_out + tap / 3) : r_out;
        const int ws   = (TAPS > 1) ? (w + tap % 3) : w;
        af[mf] = *(const f16x8*)(smem + ((rrow * WSL + ws) * 4 + (g ^ (ws & 3))) * 16);
      }
#pragma unroll
      for (int nf = 0; nf < 4; ++nf) {
        const int co = wn * 64 + nf * 16 + l15;
        bf[nf] = *(const f16x8*)(smem + XBYTES + ((co * TAPS + tap) * 4 + (g ^ (co & 3))) * 16);
      }
#pragma unroll
      for (int mf = 0; mf < 4; ++mf)
#pragma unroll
        for (int nf = 0; nf < 4; ++nf)
          acc[mf][nf] = __builtin_amdgcn_mfma_f32_16x16x32_f16(af[mf], bf[nf], acc[mf][nf], 0, 0, 0);
    }
  }

  // ---- epilogue: D row = pixel = wm*64+mf*16+4g+r, col = co = wn*64+nf*16+l15
  const int hrow = h0 + (wm >> 1);
  const int wb0  = (wm & 1) * 64;
#pragma unroll
  for (int nf = 0; nf < 4; ++nf) {
    const int co = wn * 64 + nf * 16 + l15;
    float bv = 0.f;
    if (EPI == 0 || EPI == 1 || EPI == 2 || EPI == 4) bv = bias[co];
    float sv = 0.f;
    if (EPI == 2 || EPI == 3) sv = sstyle[b * 128 + co];
#pragma unroll
    for (int mf = 0; mf < 4; ++mf) {
      const int wcol = wb0 + mf * 16 + 4 * g;
      const f32x4 v = acc[mf][nf];
      if (EPI == 4) {  // fp32 NCHW, float4 along w
        float4 o;
        o.x = lrelu(v[0] + bv); o.y = lrelu(v[1] + bv);
        o.z = lrelu(v[2] + bv); o.w = lrelu(v[3] + bv);
        *(float4*)(outf + ((size_t)(b * 128 + co) * 16384 + hrow * 128 + wcol)) = o;
      } else {
#pragma unroll
        for (int r = 0; r < 4; ++r) {
          const size_t pidx = ((size_t)((b * 128 + hrow) * 128 + (wcol + r))) * 128 + co;
          float x = v[r];
          if (EPI == 0) x += bv;
          if (EPI == 1) x = lrelu(x + bv);
          if (EPI == 2) x = (x + bv + h2f(resid[pidx])) * 0.70710678118654752f * sv;
          if (EPI == 3) x *= sv;
          outb[pidx] = f2hu(x);
        }
      }
    }
  }
}

// ---------------- launch ----------------
extern "C" void kernel_launch(void* const* d_in, const int* in_sizes, int n_in,
                              void* d_out, int out_size, void* d_ws, size_t ws_size,
                              hipStream_t stream) {
  (void)in_sizes; (void)n_in; (void)out_size; (void)ws_size;
  const float* x1       = (const float*)d_in[0];
  const float* x2       = (const float*)d_in[1];
  const float* xg       = (const float*)d_in[2];
  const float* w_mod    = (const float*)d_in[3];
  const float* b_mod    = (const float*)d_in[4];
  const float* w_style  = (const float*)d_in[5];
  const float* w_bottle = (const float*)d_in[6];
  const float* b_bottle = (const float*)d_in[7];
  const float* w_dc1    = (const float*)d_in[8];
  const float* b_dc1    = (const float*)d_in[9];
  const float* w_dc2    = (const float*)d_in[10];
  const float* b_dc2    = (const float*)d_in[11];
  const float* w_last   = (const float*)d_in[12];
  const float* b_last   = (const float*)d_in[13];
  float* out = (float*)d_out;

  char* ws = (char*)d_ws;
  float* s_in           = (float*)(ws + OFF_SIN);
  float* dscale         = (float*)(ws + OFF_DS);
  float* zerob          = (float*)(ws + OFF_ZERO);
  float* w2buf          = (float*)(ws + OFF_W2);
  unsigned short* wpk   = (unsigned short*)(ws + OFF_WPK);
  unsigned short* wb    = (unsigned short*)(ws + OFF_WB);
  unsigned short* xcat  = (unsigned short*)(ws + OFF_XCAT);
  unsigned short* xb    = (unsigned short*)(ws + OFF_XB);
  unsigned short* y1    = (unsigned short*)(ws + OFF_Y1);
  unsigned short* xr    = xcat;  // reuse (xcat dead after bottleneck)
  unsigned short* xglob = xb;    // reuse (xb dead after dc2 residual)

  prep1_kernel<<<2753, 256, 0, stream>>>(xg, w_mod, b_mod, w_style, w_dc1, w_dc2,
                                         w_last, w_bottle, wpk, wb, s_in, w2buf, zerob);
  prep2_kernel<<<256, 256, 0, stream>>>(s_in, w2buf, dscale);
  upcat_kernel<<<1024, 256, 0, stream>>>(x2, x1, xcat);
  conv_mfma<1, 256, 0><<<512, 512, 0, stream>>>(xcat, wb, b_bottle, nullptr, nullptr, xb, nullptr, zerob);
  conv_mfma<9, 128, 1><<<512, 512, 0, stream>>>(xb, wpk, b_dc1, nullptr, nullptr, y1, nullptr, zerob);
  conv_mfma<9, 128, 2><<<512, 512, 0, stream>>>(y1, wpk + 147456, b_dc2, s_in, xb, xr, nullptr, zerob);
  conv_mfma<9, 128, 3><<<512, 512, 0, stream>>>(xr, wpk + 2 * 147456, nullptr, dscale, nullptr, xglob, nullptr, zerob);
  conv_mfma<9, 128, 4><<<512, 512, 0, stream>>>(xglob, wpk + 3 * 147456, b_last, nullptr, nullptr, nullptr, out, zerob);
}